// Round 9
// baseline (119.139 us; speedup 1.0000x reference)
//
#include <hip/hip_runtime.h>

// IFNeuron forward: x[T*B, C, H, W] fp32, T=4.
// Per neuron i (slice S = N/T): mem += x[t*S+i]/vth; spk = mem>=1; mem -= spk;
// out[t*S+i] = spk*vth.  vth==1.0 -> multiply-by-reciprocal bit-exact.
//
// Model (fits R3-R8): harness fills 1 GiB of d_ws (poison) between replays ->
// caches start all-dirty; x-load allocations force 134 MB dirty writebacks.
// Unavoidable traffic 402 MB; every config measures ~5 TB/s effective ->
// 80.7 us. fillBuffer proves pure-write phases run 6.9 TB/s. This round:
// phase-separate -> K1 pure-read toucher (x becomes L3-resident),
// K2 = winner kernel (L3-hit loads + NT-store write phase).

typedef float f32x4 __attribute__((ext_vector_type(4)));

constexpr int T_STEPS = 4;
constexpr int ITEMS   = 2;   // f32x4 items per thread (R3 winner config)
constexpr int BLOCK   = 256;

// K1: stream all of x through the read path so it lands in L3.
// asm sink keeps loads live (DCE rule: ablation-via-skip deletes upstream ops).
__global__ __launch_bounds__(BLOCK) void x_toucher(
    const f32x4* __restrict__ x, size_t n4_total)
{
    size_t stride = (size_t)gridDim.x * BLOCK;
    for (size_t i = (size_t)blockIdx.x * BLOCK + threadIdx.x; i < n4_total; i += stride) {
        f32x4 v = x[i];
        asm volatile("" :: "v"(v.x), "v"(v.y), "v"(v.z), "v"(v.w));
    }
}

__global__ __launch_bounds__(BLOCK) void if_neuron_fwd(
    const f32x4* __restrict__ x,
    const float* __restrict__ vth_p,
    f32x4*       __restrict__ y,
    int n4 /* f32x4 elems per timestep slice */)
{
    const float vth = vth_p[0];
    const float inv = 1.0f / vth;   // one divide per thread; exact for vth==1.0

    const int base = blockIdx.x * (BLOCK * ITEMS) + threadIdx.x;

    f32x4 v[ITEMS][T_STEPS];
    #pragma unroll
    for (int k = 0; k < ITEMS; ++k) {
        const int i = base + k * BLOCK;
        if (i < n4) {
            #pragma unroll
            for (int t = 0; t < T_STEPS; ++t)
                v[k][t] = x[(size_t)t * n4 + i];   // L3-resident after K1
        }
    }

    #pragma unroll
    for (int k = 0; k < ITEMS; ++k) {
        const int i = base + k * BLOCK;
        if (i >= n4) continue;
        f32x4 m = (f32x4){0.f, 0.f, 0.f, 0.f};
        #pragma unroll
        for (int t = 0; t < T_STEPS; ++t) {
            const f32x4 u = v[k][t];
            f32x4 o;
            #pragma unroll
            for (int c = 0; c < 4; ++c) {
                m[c] += u[c] * inv;
                float s = (m[c] >= 1.0f) ? 1.0f : 0.0f;
                m[c] -= s;
                o[c] = s * vth;
            }
            __builtin_nontemporal_store(o, &y[(size_t)t * n4 + i]);
        }
    }
}

extern "C" void kernel_launch(void* const* d_in, const int* in_sizes, int n_in,
                              void* d_out, int out_size, void* d_ws, size_t ws_size,
                              hipStream_t stream) {
    const float* x   = (const float*)d_in[0];
    const float* vth = (const float*)d_in[1];
    float*       out = (float*)d_out;

    const int n_total = in_sizes[0];              // 512*512*16*16 = 33,554,432
    const int slice   = n_total / T_STEPS;        // floats per timestep slice
    const int n4      = slice / 4;                // f32x4 per slice = 2,097,152
    const size_t n4_total = (size_t)n_total / 4;  // all of x as f32x4

    // K1: pure-read phase (grid-stride, 2048 blocks = 8 per CU)
    x_toucher<<<2048, BLOCK, 0, stream>>>((const f32x4*)x, n4_total);

    // K2: compute + NT-store write phase
    const int per_block = BLOCK * ITEMS;          // 512 f32x4 per block
    const int grid      = (n4 + per_block - 1) / per_block;   // 4096
    if_neuron_fwd<<<grid, BLOCK, 0, stream>>>(
        (const f32x4*)x, vth, (f32x4*)out, n4);
}

// Round 10
// 80.867 us; speedup vs baseline: 1.4733x; 1.4733x over previous
//
#include <hip/hip_runtime.h>

// IFNeuron forward: x[T*B, C, H, W] fp32, T=4.
// Per neuron i (slice S = N/T): mem += x[t*S+i]/vth; spk = mem>=1; mem -= spk;
// out[t*S+i] = spk*vth.  vth==1.0 -> multiply-by-reciprocal bit-exact.
//
// FINAL config — measured ledger (timed dur, µs):
//   cached-load / nt-store, ITEMS=2   80.7  <- winner (this kernel)
//   cached-load / nt-store, ITEMS=4   81.6  (MLP null)
//   nt-load    / nt-store             98.5  (nt load path ~half-rate)
//   cached     / cached              106.7  (store allocations thrash dirty L2/L3)
//   mixed-nt-load / cached           106.7  (L3-capacity model falsified)
//   read-toucher + this kernel       119.1  (L3 residency gives 0 for streaming)
// Roofline accounting: 134 MB read + 134 MB forced dirty-poison eviction
// (harness's 1 GiB fill leaves caches dirty) + 134 MB NT write = 402 MB at
// 4.98 TB/s effective = 79% of achievable D2D; pure-phase ceilings measured
// on this box: fill 6.9 TB/s, read+evict 7.0 TB/s. Mixed-stream derating.

typedef float f32x4 __attribute__((ext_vector_type(4)));

constexpr int T_STEPS = 4;
constexpr int ITEMS   = 2;   // f32x4 items per thread
constexpr int BLOCK   = 256;

__global__ __launch_bounds__(BLOCK) void if_neuron_fwd(
    const f32x4* __restrict__ x,
    const float* __restrict__ vth_p,
    f32x4*       __restrict__ y,
    int n4 /* f32x4 elems per timestep slice */)
{
    const float vth = vth_p[0];
    const float inv = 1.0f / vth;   // one divide per thread; exact for vth==1.0

    const int base = blockIdx.x * (BLOCK * ITEMS) + threadIdx.x;

    // Issue all loads up front: ITEMS*T independent, per-instruction coalesced.
    f32x4 v[ITEMS][T_STEPS];
    #pragma unroll
    for (int k = 0; k < ITEMS; ++k) {
        const int i = base + k * BLOCK;
        if (i < n4) {
            #pragma unroll
            for (int t = 0; t < T_STEPS; ++t)
                v[k][t] = x[(size_t)t * n4 + i];   // cached loads (fastest path)
        }
    }

    #pragma unroll
    for (int k = 0; k < ITEMS; ++k) {
        const int i = base + k * BLOCK;
        if (i >= n4) continue;
        f32x4 m = (f32x4){0.f, 0.f, 0.f, 0.f};
        #pragma unroll
        for (int t = 0; t < T_STEPS; ++t) {
            const f32x4 u = v[k][t];
            f32x4 o;

            #pragma unroll
            for (int c = 0; c < 4; ++c) {
                m[c] += u[c] * inv;
                float s = (m[c] >= 1.0f) ? 1.0f : 0.0f;
                m[c] -= s;
                o[c] = s * vth;
            }

            // NT store: y never allocates in L2/L3 -> no extra dirty evictions.
            __builtin_nontemporal_store(o, &y[(size_t)t * n4 + i]);
        }
    }
}

extern "C" void kernel_launch(void* const* d_in, const int* in_sizes, int n_in,
                              void* d_out, int out_size, void* d_ws, size_t ws_size,
                              hipStream_t stream) {
    const float* x   = (const float*)d_in[0];
    const float* vth = (const float*)d_in[1];
    float*       out = (float*)d_out;

    const int n_total = in_sizes[0];              // 512*512*16*16 = 33,554,432
    const int slice   = n_total / T_STEPS;        // floats per timestep slice
    const int n4      = slice / 4;                // f32x4 per slice = 2,097,152

    const int per_block = BLOCK * ITEMS;          // 512 f32x4 per block
    const int grid      = (n4 + per_block - 1) / per_block;   // 4096

    if_neuron_fwd<<<grid, BLOCK, 0, stream>>>(
        (const f32x4*)x, vth, (f32x4*)out, n4);
}